// Round 3
// baseline (331.624 us; speedup 1.0000x reference)
//
#include <hip/hip_runtime.h>
#include <hip/hip_fp16.h>

#define QN 900
#define CN 91
#define TOTN (QN * CN)   // 81900
#define KSEL 300
#define BN 4
#define OUTW 448
#define MASKPIX (OUTW * OUTW)        // 200704
#define OFFS_LABELS (BN * KSEL)      // 1200
#define OFFS_BOXES  (2 * BN * KSEL)  // 2400
#define OFFS_MASKS  (6 * BN * KSEL)  // 7200
#define MAXC 1024
#define BT 1024
#define NWAVE (BT / 64)

static __device__ __forceinline__ unsigned fkey(float f) {
    unsigned u = __float_as_uint(f);
    return (u & 0x80000000u) ? ~u : (u | 0x80000000u);
}
static __device__ __forceinline__ float f16r(float v) {
    return __half2float(__float2half(v));
}

__global__ __launch_bounds__(BT) void select_kernel(
    const float* __restrict__ logits, const float* __restrict__ boxes,
    const int* __restrict__ tsz, float* out, int* qsel)
{
    const int b = blockIdx.x;
    const int tid = threadIdx.x;
    const int wid = tid >> 6;
    const float* lg = logits + (size_t)b * TOTN;

    __shared__ unsigned h16[NWAVE][256];   // privatized round-0 histograms
    __shared__ unsigned hist[256];
    __shared__ int sh_bin, sh_want;
    __shared__ unsigned sh_cnt;
    __shared__ int cidx[MAXC];
    __shared__ unsigned ckey[MAXC];

    // ---- round 0: privatized 256-bin histogram on top byte ----
    for (int w = 0; w < NWAVE; ++w)
        if (tid < 256) h16[w][tid] = 0;   // note: only first 256 threads zero all slices
    // (zero via strided loop instead, covering all slices)
    __syncthreads();
    for (int i = tid; i < NWAVE * 256; i += BT)
        ((unsigned*)h16)[i] = 0;
    __syncthreads();
    for (int i = tid; i < TOTN; i += BT) {
        unsigned key = fkey(lg[i]);
        atomicAdd(&h16[wid][key >> 24], 1u);
    }
    __syncthreads();
    if (tid < 256) {
        unsigned s = 0;
        for (int w = 0; w < NWAVE; ++w) s += h16[w][tid];
        hist[tid] = s;
    }
    __syncthreads();

    unsigned prefix = 0;
    int want = KSEL;
    for (int round = 0; round < 4; ++round) {
        const int shift = 24 - 8 * round;
        if (round > 0) {
            const unsigned pmask = 0xFFFFFFFFu << (shift + 8);
            if (tid < 256) hist[tid] = 0;
            __syncthreads();
            for (int i = tid; i < TOTN; i += BT) {
                unsigned key = fkey(lg[i]);
                if ((key & pmask) == prefix)
                    atomicAdd(&hist[(key >> shift) & 255u], 1u);
            }
            __syncthreads();
        }
        if (tid == 0) {
            int acc = 0;
            int bin = 255;
            for (; bin > 0; --bin) {
                int c = (int)hist[bin];
                if (acc + c >= want) break;
                acc += c;
            }
            sh_bin = bin;
            sh_want = want - acc;
        }
        __syncthreads();
        prefix |= ((unsigned)sh_bin << shift);
        want = sh_want;
        __syncthreads();
    }
    const unsigned T = prefix;

    // ---- gather candidates key >= T (~300 + rare exact dups) ----
    if (tid == 0) sh_cnt = 0;
    __syncthreads();
    for (int i = tid; i < TOTN; i += BT) {
        unsigned key = fkey(lg[i]);
        if (key >= T) {
            unsigned pos = atomicAdd(&sh_cnt, 1u);
            if (pos < MAXC) { cidx[pos] = i; ckey[pos] = key; }
        }
    }
    __syncthreads();
    const int ncand = min((int)sh_cnt, MAXC);

    const float fh = (float)tsz[b * 2 + 0];
    const float fw = (float)tsz[b * 2 + 1];

    // ---- exact rank (desc key, asc index) -> direct scatter ----
    for (int c = tid; c < ncand; c += BT) {
        const unsigned kc = ckey[c];
        const int ic = cidx[c];
        int rank = 0;
        for (int s = 0; s < ncand; ++s) {
            unsigned ks = ckey[s];
            if (ks > kc || (ks == kc && cidx[s] < ic)) ++rank;
        }
        if (rank < KSEL) {
            float lf = lg[ic];
            float score = 1.0f / (1.0f + expf(-lf));
            int q = ic / CN;
            int label = ic - q * CN;

            out[b * KSEL + rank] = score;
            out[OFFS_LABELS + b * KSEL + rank] = (float)label;

            const float* bx = boxes + ((size_t)b * QN + q) * 4;
            float cx = bx[0], cy = bx[1], ww = bx[2], hh = bx[3];
            float* ob = out + OFFS_BOXES + ((size_t)(b * KSEL + rank)) * 4;
            ob[0] = (cx - 0.5f * ww) * fw;
            ob[1] = (cy - 0.5f * hh) * fh;
            ob[2] = (cx + 0.5f * ww) * fw;
            ob[3] = (cy + 0.5f * hh) * fh;

            qsel[b * KSEL + rank] = q;
        }
    }
}

// ---- mask resize: SPLIT blocks per mask, zero barriers in the store loop ----
#define SPLIT 2
#define ROWSB (OUTW / SPLIT)   // 224 output rows per block

__global__ __launch_bounds__(256) void mask_kernel(
    const float* __restrict__ masks, const int* __restrict__ qsel, float* out)
{
    const int mk = blockIdx.x >> 1;        // 0..BN*KSEL-1
    const int part = blockIdx.x & 1;
    const int b = mk / KSEL;
    const int q = qsel[mk];
    const float* src = masks + ((size_t)b * QN + q) * 784;

    __shared__ float sm[784];
    __shared__ float vr[ROWSB][29];        // vertical-lerp result rows

    for (int i = threadIdx.x; i < 784; i += 256)
        sm[i] = f16r(src[i]);              // ref casts to f16 before resize
    __syncthreads();

    const int ybase = part * ROWSB;

    // vertical pass: 224 rows x 28 cols
    for (int t = threadIdx.x; t < ROWSB * 28; t += 256) {
        int rr = t / 28, c = t % 28;
        int y = ybase + rr;
        float sy = y * 0.0625f - 0.46875f;
        float yf = floorf(sy);
        float ty = sy - yf;
        int iy = (int)yf;
        int ylo = iy < 0 ? 0 : iy;
        int yhi = (iy + 1 > 27) ? 27 : iy + 1;
        float a = sm[ylo * 28 + c];
        float bb = sm[yhi * 28 + c];
        vr[rr][c] = a + ty * (bb - a);
    }
    __syncthreads();

    float* obase = out + OFFS_MASKS + (size_t)mk * MASKPIX + (size_t)ybase * OUTW;

    // pure store loop: 224*112 float4-groups / 256 threads = 98 iters, no barriers
#pragma unroll 2
    for (int i = 0; i < (ROWSB * 112) / 256; ++i) {
        int idx = threadIdx.x + i * 256;
        int rr = idx / 112;
        int g = idx - rr * 112;
        float px[4];
#pragma unroll
        for (int j = 0; j < 4; ++j) {
            int x = g * 4 + j;
            float sx = x * 0.0625f - 0.46875f;
            float xf = floorf(sx);
            float tx = sx - xf;
            int ix = (int)xf;
            int xlo = ix < 0 ? 0 : ix;
            int xhi = (ix + 1 > 27) ? 27 : ix + 1;
            float a = vr[rr][xlo];
            float bb = vr[rr][xhi];
            px[j] = f16r(a + tx * (bb - a));   // ref output dtype is f16
        }
        float4 w;
        w.x = px[0]; w.y = px[1]; w.z = px[2]; w.w = px[3];
        *reinterpret_cast<float4*>(obase + (size_t)rr * OUTW + g * 4) = w;
    }
}

extern "C" void kernel_launch(void* const* d_in, const int* in_sizes, int n_in,
                              void* d_out, int out_size, void* d_ws, size_t ws_size,
                              hipStream_t stream) {
    const float* pred_logits = (const float*)d_in[0];
    const float* pred_boxes  = (const float*)d_in[1];
    const float* pred_masks  = (const float*)d_in[2];
    const int*   target_sz   = (const int*)d_in[3];
    float* out = (float*)d_out;
    int* qsel = (int*)d_ws;

    select_kernel<<<BN, BT, 0, stream>>>(pred_logits, pred_boxes, target_sz, out, qsel);
    mask_kernel<<<BN * KSEL * SPLIT, 256, 0, stream>>>(pred_masks, qsel, out);
}

// Round 6
// 310.266 us; speedup vs baseline: 1.0688x; 1.0688x over previous
//
#include <hip/hip_runtime.h>
#include <hip/hip_fp16.h>

#define QN 900
#define CN 91
#define TOTN (QN * CN)   // 81900
#define KSEL 300
#define BN 4
#define OUTW 448
#define MASKPIX (OUTW * OUTW)        // 200704
#define OFFS_LABELS (BN * KSEL)      // 1200
#define OFFS_BOXES  (2 * BN * KSEL)  // 2400
#define OFFS_MASKS  (6 * BN * KSEL)  // 7200
#define MAXC 1024
#define BT 1024
#define NWAVE (BT / 64)

typedef float floatx4 __attribute__((ext_vector_type(4)));

static __device__ __forceinline__ unsigned fkey(float f) {
    unsigned u = __float_as_uint(f);
    return (u & 0x80000000u) ? ~u : (u | 0x80000000u);
}

// ---- selection: radix-select threshold + exact-rank scatter (round-3 proven) ----
__global__ __launch_bounds__(BT) void select_kernel(
    const float* __restrict__ logits, const float* __restrict__ boxes,
    const int* __restrict__ tsz, float* out, int* qsel)
{
    const int b = blockIdx.x;
    const int tid = threadIdx.x;
    const int wid = tid >> 6;
    const float* lg = logits + (size_t)b * TOTN;

    __shared__ unsigned h16[NWAVE][256];   // privatized round-0 histograms
    __shared__ unsigned hist[256];
    __shared__ int sh_bin, sh_want;
    __shared__ unsigned sh_cnt;
    __shared__ int cidx[MAXC];
    __shared__ unsigned ckey[MAXC];

    for (int i = tid; i < NWAVE * 256; i += BT)
        ((unsigned*)h16)[i] = 0;
    __syncthreads();
    for (int i = tid; i < TOTN; i += BT) {
        unsigned key = fkey(lg[i]);
        atomicAdd(&h16[wid][key >> 24], 1u);
    }
    __syncthreads();
    if (tid < 256) {
        unsigned s = 0;
        for (int w = 0; w < NWAVE; ++w) s += h16[w][tid];
        hist[tid] = s;
    }
    __syncthreads();

    unsigned prefix = 0;
    int want = KSEL;
    for (int round = 0; round < 4; ++round) {
        const int shift = 24 - 8 * round;
        if (round > 0) {
            const unsigned pmask = 0xFFFFFFFFu << (shift + 8);
            if (tid < 256) hist[tid] = 0;
            __syncthreads();
            for (int i = tid; i < TOTN; i += BT) {
                unsigned key = fkey(lg[i]);
                if ((key & pmask) == prefix)
                    atomicAdd(&hist[(key >> shift) & 255u], 1u);
            }
            __syncthreads();
        }
        if (tid == 0) {
            int acc = 0;
            int bin = 255;
            for (; bin > 0; --bin) {
                int c = (int)hist[bin];
                if (acc + c >= want) break;
                acc += c;
            }
            sh_bin = bin;
            sh_want = want - acc;
        }
        __syncthreads();
        prefix |= ((unsigned)sh_bin << shift);
        want = sh_want;
        __syncthreads();
    }
    const unsigned T = prefix;

    if (tid == 0) sh_cnt = 0;
    __syncthreads();
    for (int i = tid; i < TOTN; i += BT) {
        unsigned key = fkey(lg[i]);
        if (key >= T) {
            unsigned pos = atomicAdd(&sh_cnt, 1u);
            if (pos < MAXC) { cidx[pos] = i; ckey[pos] = key; }
        }
    }
    __syncthreads();
    const int ncand = min((int)sh_cnt, MAXC);

    const float fh = (float)tsz[b * 2 + 0];
    const float fw = (float)tsz[b * 2 + 1];

    for (int c = tid; c < ncand; c += BT) {
        const unsigned kc = ckey[c];
        const int ic = cidx[c];
        int rank = 0;
        for (int s = 0; s < ncand; ++s) {
            unsigned ks = ckey[s];
            if (ks > kc || (ks == kc && cidx[s] < ic)) ++rank;
        }
        if (rank < KSEL) {
            float lf = lg[ic];
            float score = 1.0f / (1.0f + expf(-lf));
            int q = ic / CN;
            int label = ic - q * CN;

            out[b * KSEL + rank] = score;
            out[OFFS_LABELS + b * KSEL + rank] = (float)label;

            const float* bx = boxes + ((size_t)b * QN + q) * 4;
            float cx = bx[0], cy = bx[1], ww = bx[2], hh = bx[3];
            float* ob = out + OFFS_BOXES + ((size_t)(b * KSEL + rank)) * 4;
            ob[0] = (cx - 0.5f * ww) * fw;
            ob[1] = (cy - 0.5f * hh) * fh;
            ob[2] = (cx + 0.5f * ww) * fw;
            ob[3] = (cy + 0.5f * hh) * fh;

            qsel[b * KSEL + rank] = q;
        }
    }
}

// ---- mask resize: LDS-free, barrier-free, direct L1-cached gather ----
#define SPLIT 4
#define ROWSB (OUTW / SPLIT)   // 112 rows per block

__global__ __launch_bounds__(256) void mask_kernel(
    const float* __restrict__ masks, const int* __restrict__ qsel,
    float* __restrict__ out)
{
    const int mk = blockIdx.x >> 2;        // 0..BN*KSEL-1
    const int part = blockIdx.x & 3;
    const int b = mk / KSEL;
    const int q = qsel[mk];
    const float* __restrict__ src = masks + ((size_t)b * QN + q) * 784;

    const int j = threadIdx.x & 127;       // float4-group within row (0..111 active)
    const int rhalf = threadIdx.x >> 7;    // which of 2 interleaved rows
    if (j >= 112) return;

    // hoisted column geometry: x = 16*i4 + 4*qd + m shares one column pair per quad
    const int qd = j & 3;
    const int i4 = j >> 2;
    const int c0 = i4 - 1 + (qd >> 1);
    const int c0c = c0 < 0 ? 0 : c0;
    const int c1c = (c0 + 1 > 27) ? 27 : c0 + 1;
    const float toff = 0.25f * (float)qd - ((qd >= 2) ? 1.0f : 0.0f);
    const float t0 = 0.53125f + toff, t1 = 0.59375f + toff,
                t2 = 0.65625f + toff, t3 = 0.71875f + toff;

    const int ybase = part * ROWSB + rhalf;
    float* optr = out + OFFS_MASKS + (size_t)mk * MASKPIX
                + (size_t)ybase * OUTW + j * 4;

    float sy = (float)ybase * 0.0625f - 0.46875f;   // exact multiples of 2^-6
    for (int k = 0; k < ROWSB / 2; ++k) {
        float yf = floorf(sy);
        float ty = sy - yf;
        int iy = (int)yf;
        int y0 = iy < 0 ? 0 : iy;
        int y1 = (iy + 1 > 27) ? 27 : iy + 1;
        const float* r0 = src + y0 * 28;
        const float* r1 = src + y1 * 28;
        float m00 = r0[c0c], m01 = r0[c1c];
        float m10 = r1[c0c], m11 = r1[c1c];
        float v0 = fmaf(ty, m10 - m00, m00);
        float v1 = fmaf(ty, m11 - m01, m01);
        float dv = v1 - v0;
        floatx4 w;
        w.x = fmaf(t0, dv, v0);
        w.y = fmaf(t1, dv, v0);
        w.z = fmaf(t2, dv, v0);
        w.w = fmaf(t3, dv, v0);
        __builtin_nontemporal_store(w, reinterpret_cast<floatx4*>(optr));
        optr += 2 * OUTW;
        sy += 0.125f;
    }
}

extern "C" void kernel_launch(void* const* d_in, const int* in_sizes, int n_in,
                              void* d_out, int out_size, void* d_ws, size_t ws_size,
                              hipStream_t stream) {
    const float* pred_logits = (const float*)d_in[0];
    const float* pred_boxes  = (const float*)d_in[1];
    const float* pred_masks  = (const float*)d_in[2];
    const int*   target_sz   = (const int*)d_in[3];
    float* out = (float*)d_out;
    int* qsel = (int*)d_ws;

    select_kernel<<<BN, BT, 0, stream>>>(pred_logits, pred_boxes, target_sz, out, qsel);
    mask_kernel<<<BN * KSEL * SPLIT, 256, 0, stream>>>(pred_masks, qsel, out);
}